// Round 2
// baseline (3060.181 us; speedup 1.0000x reference)
//
#include <hip/hip_runtime.h>

// GraphNN: 3-layer weighted-mean GCN, N=100000 nodes, E=1000000 edges, d=64.
// Inputs: x[N,64] f32, edge_index[2,E] int32, edge_weight[E] f32,
//         (Wl,bl,Wr) x3 (64x64, 64, 64x64) f32. Output: [N,64] f32.

static constexpr int kD = 64;

// deg[c] += ew[e]; cnt[c] += 1
__global__ __launch_bounds__(256) void k_edge_deg(
    const int* __restrict__ col, const float* __restrict__ ew,
    float* __restrict__ deg, float* __restrict__ cnt, int E) {
  int e = blockIdx.x * 256 + threadIdx.x;
  if (e >= E) return;
  int c = col[e];
  unsafeAtomicAdd(&deg[c], ew[e]);
  unsafeAtomicAdd(&cnt[c], 1.0f);
}

// deg -> dis (in place), cnt -> 1/max(cnt,1) (in place)
__global__ __launch_bounds__(256) void k_node_pre(
    float* __restrict__ deg, float* __restrict__ cnt, int N) {
  int n = blockIdx.x * 256 + threadIdx.x;
  if (n >= N) return;
  float d = deg[n];
  deg[n] = (d > 0.0f) ? rsqrtf(d) : 0.0f;
  float c = cnt[n];
  cnt[n] = 1.0f / fmaxf(c, 1.0f);
}

// w[e] = dis[row]*ew*dis[col]  (reused by all 3 layers)
__global__ __launch_bounds__(256) void k_edge_w(
    const int* __restrict__ row, const int* __restrict__ col,
    const float* __restrict__ ew, const float* __restrict__ dis,
    float* __restrict__ w, int E) {
  int e = blockIdx.x * 256 + threadIdx.x;
  if (e >= E) return;
  w[e] = dis[row[e]] * ew[e] * dis[col[e]];
}

// B[col[e]] += w[e] * A[row[e]]   (16 threads/edge, float4 per thread)
__global__ __launch_bounds__(256) void k_scatter(
    const float* __restrict__ A, float* __restrict__ B,
    const int* __restrict__ row, const int* __restrict__ col,
    const float* __restrict__ w, int E) {
  int t = blockIdx.x * 256 + threadIdx.x;
  int e = t >> 4;
  if (e >= E) return;
  int f = (t & 15) << 2;
  int r = row[e];
  int c = col[e];
  float we = w[e];
  const float4 v = *reinterpret_cast<const float4*>(A + (size_t)r * kD + f);
  float* dst = B + (size_t)c * kD + f;
  unsafeAtomicAdd(dst + 0, we * v.x);
  unsafeAtomicAdd(dst + 1, we * v.y);
  unsafeAtomicAdd(dst + 2, we * v.z);
  unsafeAtomicAdd(dst + 3, we * v.w);
}

// B[i] = relu?( (B[i]*cntinv[i]) @ Wl^T + bl + A[i] @ Wr^T )   in place.
// One wave per row; weights transposed in LDS with stride 65 (bank-conflict-free).
__global__ __launch_bounds__(256) void k_transform(
    float* __restrict__ B, const float* __restrict__ A,
    const float* __restrict__ Wl, const float* __restrict__ bl,
    const float* __restrict__ Wr, const float* __restrict__ cntinv,
    int N, int relu) {
  __shared__ float sWlt[kD * 65];
  __shared__ float sWrt[kD * 65];
  __shared__ float sbl[kD];
  __shared__ float sRow[4][2][kD];
  int tid = threadIdx.x;
  for (int idx = tid; idx < kD * kD; idx += 256) {
    int j = idx >> 6;   // output feature
    int k = idx & 63;   // input feature
    sWlt[k * 65 + j] = Wl[idx];
    sWrt[k * 65 + j] = Wr[idx];
  }
  if (tid < kD) sbl[tid] = bl[tid];
  __syncthreads();

  int wave = tid >> 6;
  int lane = tid & 63;
  int rowi = blockIdx.x * 4 + wave;
  if (rowi >= N) return;

  float ci = cntinv[rowi];
  sRow[wave][0][lane] = B[(size_t)rowi * kD + lane] * ci;  // scaled agg
  sRow[wave][1][lane] = A[(size_t)rowi * kD + lane];       // h_prev
  // wave-local LDS producer/consumer: compiler inserts lgkmcnt waits.

  float acc = sbl[lane];
#pragma unroll
  for (int k = 0; k < kD; ++k) {
    acc += sRow[wave][0][k] * sWlt[k * 65 + lane]
         + sRow[wave][1][k] * sWrt[k * 65 + lane];
  }
  if (relu) acc = fmaxf(acc, 0.0f);
  B[(size_t)rowi * kD + lane] = acc;
}

extern "C" void kernel_launch(void* const* d_in, const int* in_sizes, int n_in,
                              void* d_out, int out_size, void* d_ws, size_t ws_size,
                              hipStream_t stream) {
  const float* x   = (const float*)d_in[0];
  const int*   ei  = (const int*)d_in[1];
  const float* ew  = (const float*)d_in[2];
  const float* Wl0 = (const float*)d_in[3];
  const float* bl0 = (const float*)d_in[4];
  const float* Wr0 = (const float*)d_in[5];
  const float* Wl1 = (const float*)d_in[6];
  const float* bl1 = (const float*)d_in[7];
  const float* Wr1 = (const float*)d_in[8];
  const float* Wl2 = (const float*)d_in[9];
  const float* bl2 = (const float*)d_in[10];
  const float* Wr2 = (const float*)d_in[11];
  float* out = (float*)d_out;

  const int N = in_sizes[0] / kD;
  const int E = in_sizes[2];

  const int* row = ei;       // edge_index[0]
  const int* col = ei + E;   // edge_index[1]

  // workspace layout (floats): w[E] | deg[N] | cnt[N] | hbuf[N*64]
  float* w    = (float*)d_ws;
  float* deg  = w + E;
  float* cnt  = deg + N;
  float* hbuf = cnt + N;

  const int eb = (E + 255) / 256;
  const int nb = (N + 255) / 256;
  const int sb = (E * 16 + 255) / 256;   // scatter: 16 threads/edge
  const int tb = (N + 3) / 4;            // transform: 4 rows/block

  // --- shared normalization (edge_weight & col only) ---
  hipMemsetAsync(deg, 0, 2 * (size_t)N * sizeof(float), stream);
  k_edge_deg<<<eb, 256, 0, stream>>>(col, ew, deg, cnt, E);
  k_node_pre<<<nb, 256, 0, stream>>>(deg, cnt, N);   // deg->dis, cnt->1/max(cnt,1)
  k_edge_w<<<eb, 256, 0, stream>>>(row, col, ew, deg, w, E);

  // --- layer 0: A = x, B = out (in-place transform), relu ---
  hipMemsetAsync(out, 0, (size_t)N * kD * sizeof(float), stream);
  k_scatter<<<sb, 256, 0, stream>>>(x, out, row, col, w, E);
  k_transform<<<tb, 256, 0, stream>>>(out, x, Wl0, bl0, Wr0, cnt, N, 1);

  // --- layer 1: A = out, B = hbuf, relu ---
  hipMemsetAsync(hbuf, 0, (size_t)N * kD * sizeof(float), stream);
  k_scatter<<<sb, 256, 0, stream>>>(out, hbuf, row, col, w, E);
  k_transform<<<tb, 256, 0, stream>>>(hbuf, out, Wl1, bl1, Wr1, cnt, N, 1);

  // --- layer 2: A = hbuf, B = out, no relu ---
  hipMemsetAsync(out, 0, (size_t)N * kD * sizeof(float), stream);
  k_scatter<<<sb, 256, 0, stream>>>(hbuf, out, row, col, w, E);
  k_transform<<<tb, 256, 0, stream>>>(out, hbuf, Wl2, bl2, Wr2, cnt, N, 0);
}

// Round 5
// 1440.340 us; speedup vs baseline: 2.1246x; 2.1246x over previous
//
#include <hip/hip_runtime.h>

// GraphNN 3-layer weighted-mean GCN. N=100k, E=1M, d=64.
// CSR built once (w_e baked in); fused per-layer gather+mean+transform.
// R4: k_layer occupancy/ILP rework - weights in LDS (VGPR diet), one wave
// per node (no grid-stride), 4-way batched gather ILP in the edge loop.

static constexpr int kD = 64;
typedef unsigned int uint_t;

// ---------- CSR build ----------

__global__ __launch_bounds__(256) void k_edge_deg(
    const int* __restrict__ col, const float* __restrict__ ew,
    float* __restrict__ deg, uint_t* __restrict__ cnt, int E) {
  int e = blockIdx.x * 256 + threadIdx.x;
  if (e >= E) return;
  int c = col[e];
  unsafeAtomicAdd(&deg[c], ew[e]);
  atomicAdd(&cnt[c], 1u);
}

__global__ __launch_bounds__(256) void k_node_pre(float* __restrict__ deg, int N) {
  int n = blockIdx.x * 256 + threadIdx.x;
  if (n >= N) return;
  float d = deg[n];
  deg[n] = (d > 0.0f) ? rsqrtf(d) : 0.0f;
}

__global__ __launch_bounds__(256) void k_scanA(
    const uint_t* __restrict__ cnt, uint_t* __restrict__ incl,
    uint_t* __restrict__ bsum, int N) {
  __shared__ uint_t s[256];
  int t = threadIdx.x;
  int i = blockIdx.x * 256 + t;
  uint_t v = (i < N) ? cnt[i] : 0u;
  s[t] = v;
  __syncthreads();
  for (int off = 1; off < 256; off <<= 1) {
    uint_t tv = (t >= off) ? s[t - off] : 0u;
    __syncthreads();
    s[t] += tv;
    __syncthreads();
  }
  if (i < N) incl[i] = s[t];
  if (t == 255) bsum[blockIdx.x] = s[255];
}

__global__ __launch_bounds__(512) void k_scanB(
    const uint_t* __restrict__ bsum, uint_t* __restrict__ boff, int nb) {
  __shared__ uint_t s[512];
  int t = threadIdx.x;
  uint_t v = (t < nb) ? bsum[t] : 0u;
  s[t] = v;
  __syncthreads();
  for (int off = 1; off < 512; off <<= 1) {
    uint_t tv = (t >= off) ? s[t - off] : 0u;
    __syncthreads();
    s[t] += tv;
    __syncthreads();
  }
  if (t < nb) boff[t] = s[t] - v;  // exclusive
}

__global__ __launch_bounds__(256) void k_scanC(
    const uint_t* __restrict__ incl, const uint_t* __restrict__ cnt,
    const uint_t* __restrict__ boff, uint_t* __restrict__ rowptr, int N) {
  int i = blockIdx.x * 256 + threadIdx.x;
  if (i >= N) return;
  uint_t inc = incl[i] + boff[i >> 8];
  rowptr[i] = inc - cnt[i];
  if (i == N - 1) rowptr[N] = inc;
}

__global__ __launch_bounds__(256) void k_fill(
    const int* __restrict__ row, const int* __restrict__ col,
    const float* __restrict__ ew, const float* __restrict__ dis,
    const uint_t* __restrict__ rowptr, uint_t* __restrict__ fillcnt,
    int2* __restrict__ csr, int E) {
  int e = blockIdx.x * 256 + threadIdx.x;
  if (e >= E) return;
  int c = col[e];
  int r = row[e];
  float w = dis[r] * ew[e] * dis[c];
  uint_t pos = atomicAdd(&fillcnt[c], 1u);
  csr[rowptr[c] + pos] = make_int2(r, __float_as_int(w));
}

// ---------- fused layer ----------
// One wave per node. Weights in LDS; lane j reads row j of W as float4
// (stride 64 floats -> 2-way bank alias on b128 reads, which is free).
// Edge loop: 4 edges per step, 4 independent gathers in flight.
__global__ __launch_bounds__(256) void k_layer(
    const float* __restrict__ A, float* __restrict__ B,
    const int2* __restrict__ csr, const uint_t* __restrict__ rowptr,
    const float* __restrict__ Wl, const float* __restrict__ bl,
    const float* __restrict__ Wr, int N, int relu) {
  __shared__ float sW[2 * kD * kD];  // Wl then Wr, row-major
  __shared__ float sAgg[4][kD];
  __shared__ float sX[4][kD];
  int tid = threadIdx.x;
  int wave = tid >> 6, lane = tid & 63;

  {
    const float4* wl4 = reinterpret_cast<const float4*>(Wl);
    const float4* wr4 = reinterpret_cast<const float4*>(Wr);
    float4* s4 = reinterpret_cast<float4*>(sW);
#pragma unroll 4
    for (int i = tid; i < kD * kD / 4; i += 256) {
      s4[i] = wl4[i];
      s4[i + kD * kD / 4] = wr4[i];
    }
  }
  float bias = bl[lane];
  __syncthreads();

  int n = blockIdx.x * 4 + wave;
  if (n >= N) return;

  uint_t rb = rowptr[n];
  uint_t re = rowptr[n + 1];
  int degc = (int)(re - rb);
  float acc = 0.0f;
  for (uint_t base = rb; base < re; base += 64) {
    int m = (int)min(64u, re - base);
    int2 erw = (lane < m) ? csr[base + lane] : make_int2(0, 0);
    int i = 0;
    for (; i + 4 <= m; i += 4) {
      int r0 = __shfl(erw.x, i + 0), r1 = __shfl(erw.x, i + 1);
      int r2 = __shfl(erw.x, i + 2), r3 = __shfl(erw.x, i + 3);
      float w0 = __int_as_float(__shfl(erw.y, i + 0));
      float w1 = __int_as_float(__shfl(erw.y, i + 1));
      float w2 = __int_as_float(__shfl(erw.y, i + 2));
      float w3 = __int_as_float(__shfl(erw.y, i + 3));
      float v0 = A[(size_t)r0 * kD + lane];
      float v1 = A[(size_t)r1 * kD + lane];
      float v2 = A[(size_t)r2 * kD + lane];
      float v3 = A[(size_t)r3 * kD + lane];
      acc += w0 * v0;
      acc += w1 * v1;
      acc += w2 * v2;
      acc += w3 * v3;
    }
    for (; i < m; ++i) {
      int r = __shfl(erw.x, i);
      float w = __int_as_float(__shfl(erw.y, i));
      acc += w * A[(size_t)r * kD + lane];
    }
  }
  float ci = (degc > 0) ? (1.0f / (float)degc) : 1.0f;
  sAgg[wave][lane] = acc * ci;
  sX[wave][lane] = A[(size_t)n * kD + lane];
  // wave-local LDS producer/consumer: compiler inserts lgkmcnt waits.
  float o = bias;
  const float4* sWl4 = reinterpret_cast<const float4*>(sW + (size_t)lane * kD);
  const float4* sWr4 = reinterpret_cast<const float4*>(sW + kD * kD + (size_t)lane * kD);
#pragma unroll
  for (int k4 = 0; k4 < 16; ++k4) {
    float4 ag = *reinterpret_cast<const float4*>(&sAgg[wave][k4 * 4]);
    float4 xv = *reinterpret_cast<const float4*>(&sX[wave][k4 * 4]);
    float4 wl = sWl4[k4];
    float4 wr = sWr4[k4];
    o += ag.x * wl.x + ag.y * wl.y + ag.z * wl.z + ag.w * wl.w;
    o += xv.x * wr.x + xv.y * wr.y + xv.z * wr.z + xv.w * wr.w;
  }
  if (relu) o = fmaxf(o, 0.0f);
  B[(size_t)n * kD + lane] = o;
}

extern "C" void kernel_launch(void* const* d_in, const int* in_sizes, int n_in,
                              void* d_out, int out_size, void* d_ws, size_t ws_size,
                              hipStream_t stream) {
  const float* x   = (const float*)d_in[0];
  const int*   ei  = (const int*)d_in[1];
  const float* ew  = (const float*)d_in[2];
  const float* Wl0 = (const float*)d_in[3];
  const float* bl0 = (const float*)d_in[4];
  const float* Wr0 = (const float*)d_in[5];
  const float* Wl1 = (const float*)d_in[6];
  const float* bl1 = (const float*)d_in[7];
  const float* Wr1 = (const float*)d_in[8];
  const float* Wl2 = (const float*)d_in[9];
  const float* bl2 = (const float*)d_in[10];
  const float* Wr2 = (const float*)d_in[11];
  float* out = (float*)d_out;

  const int N = in_sizes[0] / kD;
  const int E = in_sizes[2];
  const int* row = ei;      // edge_index[0]
  const int* col = ei + E;  // edge_index[1]

  const int nb256 = (N + 255) / 256;

  // workspace layout
  char* p = (char*)d_ws;
  int2*   csr     = (int2*)p;   p += (size_t)E * sizeof(int2);
  float*  h1      = (float*)p;  p += (size_t)N * kD * sizeof(float);
  float*  deg     = (float*)p;  p += (size_t)N * sizeof(float);
  uint_t* cnt     = (uint_t*)p; p += (size_t)N * sizeof(uint_t);
  uint_t* fillcnt = (uint_t*)p; p += (size_t)N * sizeof(uint_t);
  uint_t* rowptr  = (uint_t*)p; p += (size_t)(N + 1) * sizeof(uint_t);
  uint_t* incl    = (uint_t*)p; p += (size_t)N * sizeof(uint_t);
  uint_t* bsum    = (uint_t*)p; p += (size_t)nb256 * sizeof(uint_t);
  uint_t* boff    = (uint_t*)p;

  const int eb = (E + 255) / 256;

  hipMemsetAsync(deg, 0, 3 * (size_t)N * sizeof(float), stream);
  k_edge_deg<<<eb, 256, 0, stream>>>(col, ew, deg, cnt, E);
  k_node_pre<<<nb256, 256, 0, stream>>>(deg, N);
  k_scanA<<<nb256, 256, 0, stream>>>(cnt, incl, bsum, N);
  k_scanB<<<1, 512, 0, stream>>>(bsum, boff, nb256);
  k_scanC<<<nb256, 256, 0, stream>>>(incl, cnt, boff, rowptr, N);
  k_fill<<<eb, 256, 0, stream>>>(row, col, ew, deg, rowptr, fillcnt, csr, E);

  const int lb = (N + 3) / 4;  // one wave per node
  k_layer<<<lb, 256, 0, stream>>>(x,   out, csr, rowptr, Wl0, bl0, Wr0, N, 1);
  k_layer<<<lb, 256, 0, stream>>>(out, h1,  csr, rowptr, Wl1, bl1, Wr1, N, 1);
  k_layer<<<lb, 256, 0, stream>>>(h1,  out, csr, rowptr, Wl2, bl2, Wr2, N, 0);
}

// Round 6
// 709.636 us; speedup vs baseline: 4.3123x; 2.0297x over previous
//
#include <hip/hip_runtime.h>

// GraphNN 3-layer weighted-mean GCN. N=100k, E=1M, d=64.
// CSR built once (w_e baked in); fused per-layer gather+mean+transform.
// R5: persistent 8-wave blocks, weights staged once per block in LDS with
// row pad 68 floats (conflict-free b128 reads), 4-way gather ILP, low VGPR
// -> 32 waves/CU occupancy.

static constexpr int kD = 64;
static constexpr int WPAD = 68;  // padded weight row stride (floats)
typedef unsigned int uint_t;

// ---------- CSR build ----------

__global__ __launch_bounds__(256) void k_edge_deg(
    const int* __restrict__ col, const float* __restrict__ ew,
    float* __restrict__ deg, uint_t* __restrict__ cnt, int E) {
  int e = blockIdx.x * 256 + threadIdx.x;
  if (e >= E) return;
  int c = col[e];
  unsafeAtomicAdd(&deg[c], ew[e]);
  atomicAdd(&cnt[c], 1u);
}

__global__ __launch_bounds__(256) void k_node_pre(float* __restrict__ deg, int N) {
  int n = blockIdx.x * 256 + threadIdx.x;
  if (n >= N) return;
  float d = deg[n];
  deg[n] = (d > 0.0f) ? rsqrtf(d) : 0.0f;
}

__global__ __launch_bounds__(256) void k_scanA(
    const uint_t* __restrict__ cnt, uint_t* __restrict__ incl,
    uint_t* __restrict__ bsum, int N) {
  __shared__ uint_t s[256];
  int t = threadIdx.x;
  int i = blockIdx.x * 256 + t;
  uint_t v = (i < N) ? cnt[i] : 0u;
  s[t] = v;
  __syncthreads();
  for (int off = 1; off < 256; off <<= 1) {
    uint_t tv = (t >= off) ? s[t - off] : 0u;
    __syncthreads();
    s[t] += tv;
    __syncthreads();
  }
  if (i < N) incl[i] = s[t];
  if (t == 255) bsum[blockIdx.x] = s[255];
}

__global__ __launch_bounds__(512) void k_scanB(
    const uint_t* __restrict__ bsum, uint_t* __restrict__ boff, int nb) {
  __shared__ uint_t s[512];
  int t = threadIdx.x;
  uint_t v = (t < nb) ? bsum[t] : 0u;
  s[t] = v;
  __syncthreads();
  for (int off = 1; off < 512; off <<= 1) {
    uint_t tv = (t >= off) ? s[t - off] : 0u;
    __syncthreads();
    s[t] += tv;
    __syncthreads();
  }
  if (t < nb) boff[t] = s[t] - v;  // exclusive
}

__global__ __launch_bounds__(256) void k_scanC(
    const uint_t* __restrict__ incl, const uint_t* __restrict__ cnt,
    const uint_t* __restrict__ boff, uint_t* __restrict__ rowptr, int N) {
  int i = blockIdx.x * 256 + threadIdx.x;
  if (i >= N) return;
  uint_t inc = incl[i] + boff[i >> 8];
  rowptr[i] = inc - cnt[i];
  if (i == N - 1) rowptr[N] = inc;
}

__global__ __launch_bounds__(256) void k_fill(
    const int* __restrict__ row, const int* __restrict__ col,
    const float* __restrict__ ew, const float* __restrict__ dis,
    const uint_t* __restrict__ rowptr, uint_t* __restrict__ fillcnt,
    int2* __restrict__ csr, int E) {
  int e = blockIdx.x * 256 + threadIdx.x;
  if (e >= E) return;
  int c = col[e];
  int r = row[e];
  float w = dis[r] * ew[e] * dis[c];
  uint_t pos = atomicAdd(&fillcnt[c], 1u);
  csr[rowptr[c] + pos] = make_int2(r, __float_as_int(w));
}

// ---------- fused layer ----------
// Persistent blocks: 8 waves, weights staged once per block (padded rows).
// Per wave, grid-stride over nodes: gather ~deg edges (4-way ILP), mean,
// 64x64 transform reading padded LDS weights (conflict-free b128).
__global__ __launch_bounds__(512) void k_layer(
    const float* __restrict__ A, float* __restrict__ B,
    const int2* __restrict__ csr, const uint_t* __restrict__ rowptr,
    const float* __restrict__ Wl, const float* __restrict__ bl,
    const float* __restrict__ Wr, int N, int relu, int nwaves) {
  __shared__ float sW[2 * kD * WPAD];  // Wl then Wr, row stride WPAD
  __shared__ float sAgg[8][kD];
  __shared__ float sX[8][kD];
  int tid = threadIdx.x;
  int wave = tid >> 6, lane = tid & 63;

  // stage both matrices, padded: i indexes float4 (row = i>>4, c4 = i&15)
  for (int i = tid; i < kD * 16; i += 512) {
    int r = i >> 4, c4 = i & 15;
    float4 v = reinterpret_cast<const float4*>(Wl)[i];
    float4 u = reinterpret_cast<const float4*>(Wr)[i];
    *reinterpret_cast<float4*>(&sW[r * WPAD + c4 * 4]) = v;
    *reinterpret_cast<float4*>(&sW[kD * WPAD + r * WPAD + c4 * 4]) = u;
  }
  float bias = bl[lane];
  __syncthreads();

  const float* sWl = sW + (size_t)lane * WPAD;
  const float* sWr = sW + kD * WPAD + (size_t)lane * WPAD;

  int gw = blockIdx.x * 8 + wave;
  for (int n = gw; n < N; n += nwaves) {
    uint_t rb = rowptr[n];
    uint_t re = rowptr[n + 1];
    int degc = (int)(re - rb);
    float acc = 0.0f;
    for (uint_t base = rb; base < re; base += 64) {
      int m = (int)min(64u, re - base);
      int2 erw = (lane < m) ? csr[base + lane] : make_int2(0, 0);
      int i = 0;
      for (; i + 4 <= m; i += 4) {
        int r0 = __shfl(erw.x, i + 0), r1 = __shfl(erw.x, i + 1);
        int r2 = __shfl(erw.x, i + 2), r3 = __shfl(erw.x, i + 3);
        float w0 = __int_as_float(__shfl(erw.y, i + 0));
        float w1 = __int_as_float(__shfl(erw.y, i + 1));
        float w2 = __int_as_float(__shfl(erw.y, i + 2));
        float w3 = __int_as_float(__shfl(erw.y, i + 3));
        float v0 = A[(size_t)r0 * kD + lane];
        float v1 = A[(size_t)r1 * kD + lane];
        float v2 = A[(size_t)r2 * kD + lane];
        float v3 = A[(size_t)r3 * kD + lane];
        acc += w0 * v0;
        acc += w1 * v1;
        acc += w2 * v2;
        acc += w3 * v3;
      }
      for (; i < m; ++i) {
        int r = __shfl(erw.x, i);
        float w = __int_as_float(__shfl(erw.y, i));
        acc += w * A[(size_t)r * kD + lane];
      }
    }
    float ci = (degc > 0) ? (1.0f / (float)degc) : 1.0f;
    sAgg[wave][lane] = acc * ci;
    sX[wave][lane] = A[(size_t)n * kD + lane];
    // wave-local LDS producer/consumer: compiler inserts lgkmcnt waits.
    float o = bias;
#pragma unroll
    for (int k4 = 0; k4 < 16; ++k4) {
      float4 ag = *reinterpret_cast<const float4*>(&sAgg[wave][k4 * 4]);
      float4 xv = *reinterpret_cast<const float4*>(&sX[wave][k4 * 4]);
      float4 wl = *reinterpret_cast<const float4*>(&sWl[k4 * 4]);
      float4 wr = *reinterpret_cast<const float4*>(&sWr[k4 * 4]);
      o += ag.x * wl.x + ag.y * wl.y + ag.z * wl.z + ag.w * wl.w;
      o += xv.x * wr.x + xv.y * wr.y + xv.z * wr.z + xv.w * wr.w;
    }
    if (relu) o = fmaxf(o, 0.0f);
    B[(size_t)n * kD + lane] = o;
  }
}

extern "C" void kernel_launch(void* const* d_in, const int* in_sizes, int n_in,
                              void* d_out, int out_size, void* d_ws, size_t ws_size,
                              hipStream_t stream) {
  const float* x   = (const float*)d_in[0];
  const int*   ei  = (const int*)d_in[1];
  const float* ew  = (const float*)d_in[2];
  const float* Wl0 = (const float*)d_in[3];
  const float* bl0 = (const float*)d_in[4];
  const float* Wr0 = (const float*)d_in[5];
  const float* Wl1 = (const float*)d_in[6];
  const float* bl1 = (const float*)d_in[7];
  const float* Wr1 = (const float*)d_in[8];
  const float* Wl2 = (const float*)d_in[9];
  const float* bl2 = (const float*)d_in[10];
  const float* Wr2 = (const float*)d_in[11];
  float* out = (float*)d_out;

  const int N = in_sizes[0] / kD;
  const int E = in_sizes[2];
  const int* row = ei;      // edge_index[0]
  const int* col = ei + E;  // edge_index[1]

  const int nb256 = (N + 255) / 256;

  // workspace layout
  char* p = (char*)d_ws;
  int2*   csr     = (int2*)p;   p += (size_t)E * sizeof(int2);
  float*  h1      = (float*)p;  p += (size_t)N * kD * sizeof(float);
  float*  deg     = (float*)p;  p += (size_t)N * sizeof(float);
  uint_t* cnt     = (uint_t*)p; p += (size_t)N * sizeof(uint_t);
  uint_t* fillcnt = (uint_t*)p; p += (size_t)N * sizeof(uint_t);
  uint_t* rowptr  = (uint_t*)p; p += (size_t)(N + 1) * sizeof(uint_t);
  uint_t* incl    = (uint_t*)p; p += (size_t)N * sizeof(uint_t);
  uint_t* bsum    = (uint_t*)p; p += (size_t)nb256 * sizeof(uint_t);
  uint_t* boff    = (uint_t*)p;

  const int eb = (E + 255) / 256;

  hipMemsetAsync(deg, 0, 3 * (size_t)N * sizeof(float), stream);
  k_edge_deg<<<eb, 256, 0, stream>>>(col, ew, deg, cnt, E);
  k_node_pre<<<nb256, 256, 0, stream>>>(deg, N);
  k_scanA<<<nb256, 256, 0, stream>>>(cnt, incl, bsum, N);
  k_scanB<<<1, 512, 0, stream>>>(bsum, boff, nb256);
  k_scanC<<<nb256, 256, 0, stream>>>(incl, cnt, boff, rowptr, N);
  k_fill<<<eb, 256, 0, stream>>>(row, col, ew, deg, rowptr, fillcnt, csr, E);

  // persistent: 4 blocks/CU x 256 CU = 1024 blocks, 8 waves each
  const int blocks = 1024;
  const int nwaves = blocks * 8;
  k_layer<<<blocks, 512, 0, stream>>>(x,   out, csr, rowptr, Wl0, bl0, Wr0, N, 1, nwaves);
  k_layer<<<blocks, 512, 0, stream>>>(out, h1,  csr, rowptr, Wl1, bl1, Wr1, N, 1, nwaves);
  k_layer<<<blocks, 512, 0, stream>>>(h1,  out, csr, rowptr, Wl2, bl2, Wr2, N, 0, nwaves);
}

// Round 7
// 667.665 us; speedup vs baseline: 4.5834x; 1.0629x over previous
//
#include <hip/hip_runtime.h>

// GraphNN 3-layer weighted-mean GCN. N=100k, E=1M, d=64.
// R6: vectorized gather - 4 lane-groups x 16 lanes, float4 per lane per edge
// (4x fewer VMEM instrs, 4x bytes in flight), 2-wide unroll, cross-group
// shfl_xor reduce. Weights staged once per persistent block (padded, conflict-free).

static constexpr int kD = 64;
static constexpr int WPAD = 68;
typedef unsigned int uint_t;

__global__ __launch_bounds__(256) void k_edge_deg(
    const int* __restrict__ col, const float* __restrict__ ew,
    float* __restrict__ deg, uint_t* __restrict__ cnt, int E) {
  int e = blockIdx.x * 256 + threadIdx.x;
  if (e >= E) return;
  int c = col[e];
  unsafeAtomicAdd(&deg[c], ew[e]);
  atomicAdd(&cnt[c], 1u);
}

__global__ __launch_bounds__(256) void k_node_pre(float* __restrict__ deg, int N) {
  int n = blockIdx.x * 256 + threadIdx.x;
  if (n >= N) return;
  float d = deg[n];
  deg[n] = (d > 0.0f) ? rsqrtf(d) : 0.0f;
}

__global__ __launch_bounds__(256) void k_scanA(
    const uint_t* __restrict__ cnt, uint_t* __restrict__ incl,
    uint_t* __restrict__ bsum, int N) {
  __shared__ uint_t s[256];
  int t = threadIdx.x;
  int i = blockIdx.x * 256 + t;
  uint_t v = (i < N) ? cnt[i] : 0u;
  s[t] = v;
  __syncthreads();
  for (int off = 1; off < 256; off <<= 1) {
    uint_t tv = (t >= off) ? s[t - off] : 0u;
    __syncthreads();
    s[t] += tv;
    __syncthreads();
  }
  if (i < N) incl[i] = s[t];
  if (t == 255) bsum[blockIdx.x] = s[255];
}

__global__ __launch_bounds__(512) void k_scanB(
    const uint_t* __restrict__ bsum, uint_t* __restrict__ boff, int nb) {
  __shared__ uint_t s[512];
  int t = threadIdx.x;
  uint_t v = (t < nb) ? bsum[t] : 0u;
  s[t] = v;
  __syncthreads();
  for (int off = 1; off < 512; off <<= 1) {
    uint_t tv = (t >= off) ? s[t - off] : 0u;
    __syncthreads();
    s[t] += tv;
    __syncthreads();
  }
  if (t < nb) boff[t] = s[t] - v;
}

__global__ __launch_bounds__(256) void k_scanC(
    const uint_t* __restrict__ incl, const uint_t* __restrict__ cnt,
    const uint_t* __restrict__ boff, uint_t* __restrict__ rowptr, int N) {
  int i = blockIdx.x * 256 + threadIdx.x;
  if (i >= N) return;
  uint_t inc = incl[i] + boff[i >> 8];
  rowptr[i] = inc - cnt[i];
  if (i == N - 1) rowptr[N] = inc;
}

__global__ __launch_bounds__(256) void k_fill(
    const int* __restrict__ row, const int* __restrict__ col,
    const float* __restrict__ ew, const float* __restrict__ dis,
    const uint_t* __restrict__ rowptr, uint_t* __restrict__ fillcnt,
    int2* __restrict__ csr, int E) {
  int e = blockIdx.x * 256 + threadIdx.x;
  if (e >= E) return;
  int c = col[e];
  int r = row[e];
  float w = dis[r] * ew[e] * dis[c];
  uint_t pos = atomicAdd(&fillcnt[c], 1u);
  csr[rowptr[c] + pos] = make_int2(r, __float_as_int(w));
}

// ---------- fused layer, vectorized gather ----------
__global__ __launch_bounds__(512) void k_layer(
    const float* __restrict__ A, float* __restrict__ B,
    const int2* __restrict__ csr, const uint_t* __restrict__ rowptr,
    const float* __restrict__ Wl, const float* __restrict__ bl,
    const float* __restrict__ Wr, int N, int relu, int nwaves) {
  __shared__ float sW[2 * kD * WPAD];
  __shared__ float sAgg[8][kD];
  __shared__ float sX[8][kD];
  int tid = threadIdx.x;
  int wave = tid >> 6, lane = tid & 63;
  int g = lane >> 4;      // gather group 0..3
  int l16 = lane & 15;    // lane within group

  for (int i = tid; i < kD * 16; i += 512) {
    int r = i >> 4, c4 = i & 15;
    float4 v = reinterpret_cast<const float4*>(Wl)[i];
    float4 u = reinterpret_cast<const float4*>(Wr)[i];
    *reinterpret_cast<float4*>(&sW[r * WPAD + c4 * 4]) = v;
    *reinterpret_cast<float4*>(&sW[kD * WPAD + r * WPAD + c4 * 4]) = u;
  }
  float bias = bl[lane];
  __syncthreads();

  const float* sWl = sW + (size_t)lane * WPAD;
  const float* sWr = sW + kD * WPAD + (size_t)lane * WPAD;

  int gw = blockIdx.x * 8 + wave;
  for (int n = gw; n < N; n += nwaves) {
    uint_t rb = rowptr[n];
    uint_t re = rowptr[n + 1];
    int degc = (int)(re - rb);
    float4 acc = make_float4(0.f, 0.f, 0.f, 0.f);
    for (uint_t base = rb; base < re; base += 64) {
      int m = (int)min(64u, re - base);
      // stage up to 64 edge records; lanes >= m hold (r=0, w=0) -> contribute 0
      int2 erw = (lane < m) ? csr[base + lane] : make_int2(0, 0);
      int steps = (m + 3) >> 2;
      int i = 0;
      for (; i + 2 <= steps; i += 2) {
        int s0 = i * 4 + g, s1 = (i + 1) * 4 + g;
        int r0 = __shfl(erw.x, s0);
        float w0 = __int_as_float(__shfl(erw.y, s0));
        int r1 = __shfl(erw.x, s1);
        float w1 = __int_as_float(__shfl(erw.y, s1));
        float4 v0 = *reinterpret_cast<const float4*>(A + (size_t)r0 * kD + l16 * 4);
        float4 v1 = *reinterpret_cast<const float4*>(A + (size_t)r1 * kD + l16 * 4);
        acc.x += w0 * v0.x; acc.y += w0 * v0.y; acc.z += w0 * v0.z; acc.w += w0 * v0.w;
        acc.x += w1 * v1.x; acc.y += w1 * v1.y; acc.z += w1 * v1.z; acc.w += w1 * v1.w;
      }
      for (; i < steps; ++i) {
        int s0 = i * 4 + g;
        int r0 = __shfl(erw.x, s0);
        float w0 = __int_as_float(__shfl(erw.y, s0));
        float4 v0 = *reinterpret_cast<const float4*>(A + (size_t)r0 * kD + l16 * 4);
        acc.x += w0 * v0.x; acc.y += w0 * v0.y; acc.z += w0 * v0.z; acc.w += w0 * v0.w;
      }
    }
    // reduce across the 4 groups (lanes sharing l16)
    acc.x += __shfl_xor(acc.x, 16); acc.y += __shfl_xor(acc.y, 16);
    acc.z += __shfl_xor(acc.z, 16); acc.w += __shfl_xor(acc.w, 16);
    acc.x += __shfl_xor(acc.x, 32); acc.y += __shfl_xor(acc.y, 32);
    acc.z += __shfl_xor(acc.z, 32); acc.w += __shfl_xor(acc.w, 32);
    float ci = (degc > 0) ? (1.0f / (float)degc) : 1.0f;
    if (g == 0) {
      *reinterpret_cast<float4*>(&sAgg[wave][l16 * 4]) =
          make_float4(acc.x * ci, acc.y * ci, acc.z * ci, acc.w * ci);
    }
    sX[wave][lane] = A[(size_t)n * kD + lane];
    // wave-local LDS producer/consumer: compiler inserts lgkmcnt waits.
    float o = bias;
#pragma unroll
    for (int k4 = 0; k4 < 16; ++k4) {
      float4 ag = *reinterpret_cast<const float4*>(&sAgg[wave][k4 * 4]);
      float4 xv = *reinterpret_cast<const float4*>(&sX[wave][k4 * 4]);
      float4 wl = *reinterpret_cast<const float4*>(&sWl[k4 * 4]);
      float4 wr = *reinterpret_cast<const float4*>(&sWr[k4 * 4]);
      o += ag.x * wl.x + ag.y * wl.y + ag.z * wl.z + ag.w * wl.w;
      o += xv.x * wr.x + xv.y * wr.y + xv.z * wr.z + xv.w * wr.w;
    }
    if (relu) o = fmaxf(o, 0.0f);
    B[(size_t)n * kD + lane] = o;
  }
}

extern "C" void kernel_launch(void* const* d_in, const int* in_sizes, int n_in,
                              void* d_out, int out_size, void* d_ws, size_t ws_size,
                              hipStream_t stream) {
  const float* x   = (const float*)d_in[0];
  const int*   ei  = (const int*)d_in[1];
  const float* ew  = (const float*)d_in[2];
  const float* Wl0 = (const float*)d_in[3];
  const float* bl0 = (const float*)d_in[4];
  const float* Wr0 = (const float*)d_in[5];
  const float* Wl1 = (const float*)d_in[6];
  const float* bl1 = (const float*)d_in[7];
  const float* Wr1 = (const float*)d_in[8];
  const float* Wl2 = (const float*)d_in[9];
  const float* bl2 = (const float*)d_in[10];
  const float* Wr2 = (const float*)d_in[11];
  float* out = (float*)d_out;

  const int N = in_sizes[0] / kD;
  const int E = in_sizes[2];
  const int* row = ei;
  const int* col = ei + E;

  const int nb256 = (N + 255) / 256;

  char* p = (char*)d_ws;
  int2*   csr     = (int2*)p;   p += (size_t)E * sizeof(int2);
  float*  h1      = (float*)p;  p += (size_t)N * kD * sizeof(float);
  float*  deg     = (float*)p;  p += (size_t)N * sizeof(float);
  uint_t* cnt     = (uint_t*)p; p += (size_t)N * sizeof(uint_t);
  uint_t* fillcnt = (uint_t*)p; p += (size_t)N * sizeof(uint_t);
  uint_t* rowptr  = (uint_t*)p; p += (size_t)(N + 1) * sizeof(uint_t);
  uint_t* incl    = (uint_t*)p; p += (size_t)N * sizeof(uint_t);
  uint_t* bsum    = (uint_t*)p; p += (size_t)nb256 * sizeof(uint_t);
  uint_t* boff    = (uint_t*)p;

  const int eb = (E + 255) / 256;

  hipMemsetAsync(deg, 0, 3 * (size_t)N * sizeof(float), stream);
  k_edge_deg<<<eb, 256, 0, stream>>>(col, ew, deg, cnt, E);
  k_node_pre<<<nb256, 256, 0, stream>>>(deg, N);
  k_scanA<<<nb256, 256, 0, stream>>>(cnt, incl, bsum, N);
  k_scanB<<<1, 512, 0, stream>>>(bsum, boff, nb256);
  k_scanC<<<nb256, 256, 0, stream>>>(incl, cnt, boff, rowptr, N);
  k_fill<<<eb, 256, 0, stream>>>(row, col, ew, deg, rowptr, fillcnt, csr, E);

  const int blocks = 1024;
  const int nwaves = blocks * 8;
  k_layer<<<blocks, 512, 0, stream>>>(x,   out, csr, rowptr, Wl0, bl0, Wr0, N, 1, nwaves);
  k_layer<<<blocks, 512, 0, stream>>>(out, h1,  csr, rowptr, Wl1, bl1, Wr1, N, 1, nwaves);
  k_layer<<<blocks, 512, 0, stream>>>(h1,  out, csr, rowptr, Wl2, bl2, Wr2, N, 0, nwaves);
}

// Round 8
// 666.769 us; speedup vs baseline: 4.5896x; 1.0013x over previous
//
#include <hip/hip_runtime.h>

// GraphNN 3-layer weighted-mean GCN. N=100k, E=1M, d=64.
// R7: bf16 storage for h rows (halves random-gather L2-miss bytes, the
// measured bottleneck). Math stays f32; only N x 64 feature arrays are bf16.
// CSR w/ baked weights built once; persistent 8-wave blocks; padded LDS weights.

static constexpr int kD = 64;
static constexpr int WPAD = 68;
typedef unsigned int uint_t;
typedef unsigned short ushort_t;

__device__ __forceinline__ float bf2f(ushort_t u) {
  return __uint_as_float(((uint_t)u) << 16);
}
__device__ __forceinline__ ushort_t f2bf(float f) {
  uint_t u = __float_as_uint(f);
  u += 0x7fffu + ((u >> 16) & 1u);  // RNE
  return (ushort_t)(u >> 16);
}

__global__ __launch_bounds__(256) void k_edge_deg(
    const int* __restrict__ col, const float* __restrict__ ew,
    float* __restrict__ deg, uint_t* __restrict__ cnt, int E) {
  int e = blockIdx.x * 256 + threadIdx.x;
  if (e >= E) return;
  int c = col[e];
  unsafeAtomicAdd(&deg[c], ew[e]);
  atomicAdd(&cnt[c], 1u);
}

__global__ __launch_bounds__(256) void k_node_pre(float* __restrict__ deg, int N) {
  int n = blockIdx.x * 256 + threadIdx.x;
  if (n >= N) return;
  float d = deg[n];
  deg[n] = (d > 0.0f) ? rsqrtf(d) : 0.0f;
}

__global__ __launch_bounds__(256) void k_scanA(
    const uint_t* __restrict__ cnt, uint_t* __restrict__ incl,
    uint_t* __restrict__ bsum, int N) {
  __shared__ uint_t s[256];
  int t = threadIdx.x;
  int i = blockIdx.x * 256 + t;
  uint_t v = (i < N) ? cnt[i] : 0u;
  s[t] = v;
  __syncthreads();
  for (int off = 1; off < 256; off <<= 1) {
    uint_t tv = (t >= off) ? s[t - off] : 0u;
    __syncthreads();
    s[t] += tv;
    __syncthreads();
  }
  if (i < N) incl[i] = s[t];
  if (t == 255) bsum[blockIdx.x] = s[255];
}

__global__ __launch_bounds__(512) void k_scanB(
    const uint_t* __restrict__ bsum, uint_t* __restrict__ boff, int nb) {
  __shared__ uint_t s[512];
  int t = threadIdx.x;
  uint_t v = (t < nb) ? bsum[t] : 0u;
  s[t] = v;
  __syncthreads();
  for (int off = 1; off < 512; off <<= 1) {
    uint_t tv = (t >= off) ? s[t - off] : 0u;
    __syncthreads();
    s[t] += tv;
    __syncthreads();
  }
  if (t < nb) boff[t] = s[t] - v;
}

__global__ __launch_bounds__(256) void k_scanC(
    const uint_t* __restrict__ incl, const uint_t* __restrict__ cnt,
    const uint_t* __restrict__ boff, uint_t* __restrict__ rowptr, int N) {
  int i = blockIdx.x * 256 + threadIdx.x;
  if (i >= N) return;
  uint_t inc = incl[i] + boff[i >> 8];
  rowptr[i] = inc - cnt[i];
  if (i == N - 1) rowptr[N] = inc;
}

__global__ __launch_bounds__(256) void k_fill(
    const int* __restrict__ row, const int* __restrict__ col,
    const float* __restrict__ ew, const float* __restrict__ dis,
    const uint_t* __restrict__ rowptr, uint_t* __restrict__ fillcnt,
    int2* __restrict__ csr, int E) {
  int e = blockIdx.x * 256 + threadIdx.x;
  if (e >= E) return;
  int c = col[e];
  int r = row[e];
  float w = dis[r] * ew[e] * dis[c];
  uint_t pos = atomicAdd(&fillcnt[c], 1u);
  csr[rowptr[c] + pos] = make_int2(r, __float_as_int(w));
}

// x f32 -> bf16
__global__ __launch_bounds__(256) void k_cvt(
    const float* __restrict__ x, ushort_t* __restrict__ xb, int total) {
  int i = blockIdx.x * 256 + threadIdx.x;
  if (i >= total) return;
  xb[i] = f2bf(x[i]);
}

// ---------- fused layer: bf16 rows, f32 math ----------
// 4 lane-groups x 16; per edge each lane loads uint2 (4 bf16). 4-step unroll.
__global__ __launch_bounds__(512) void k_layer(
    const ushort_t* __restrict__ A, ushort_t* __restrict__ B16,
    float* __restrict__ Bf,
    const int2* __restrict__ csr, const uint_t* __restrict__ rowptr,
    const float* __restrict__ Wl, const float* __restrict__ bl,
    const float* __restrict__ Wr, int N, int relu, int nwaves) {
  __shared__ float sW[2 * kD * WPAD];
  __shared__ float sAgg[8][kD];
  __shared__ float sX[8][kD];
  int tid = threadIdx.x;
  int wave = tid >> 6, lane = tid & 63;
  int g = lane >> 4;
  int l16 = lane & 15;

  for (int i = tid; i < kD * 16; i += 512) {
    int r = i >> 4, c4 = i & 15;
    float4 v = reinterpret_cast<const float4*>(Wl)[i];
    float4 u = reinterpret_cast<const float4*>(Wr)[i];
    *reinterpret_cast<float4*>(&sW[r * WPAD + c4 * 4]) = v;
    *reinterpret_cast<float4*>(&sW[kD * WPAD + r * WPAD + c4 * 4]) = u;
  }
  float bias = bl[lane];
  __syncthreads();

  const float* sWl = sW + (size_t)lane * WPAD;
  const float* sWr = sW + kD * WPAD + (size_t)lane * WPAD;

  int gw = blockIdx.x * 8 + wave;
  for (int n = gw; n < N; n += nwaves) {
    uint_t rb = rowptr[n];
    uint_t re = rowptr[n + 1];
    int degc = (int)(re - rb);
    float4 acc = make_float4(0.f, 0.f, 0.f, 0.f);
    for (uint_t base = rb; base < re; base += 64) {
      int m = (int)min(64u, re - base);
      int2 erw = (lane < m) ? csr[base + lane] : make_int2(0, 0);
      int steps = (m + 3) >> 2;
      int i = 0;
#define GATHER_ONE(S, ACC)                                                     \
      {                                                                        \
        int rr = __shfl(erw.x, (S));                                           \
        float ww = __int_as_float(__shfl(erw.y, (S)));                         \
        uint2 q = *reinterpret_cast<const uint2*>(A + (size_t)rr * kD + l16 * 4); \
        float f0 = __uint_as_float(q.x << 16);                                 \
        float f1 = __uint_as_float(q.x & 0xffff0000u);                         \
        float f2 = __uint_as_float(q.y << 16);                                 \
        float f3 = __uint_as_float(q.y & 0xffff0000u);                         \
        ACC.x += ww * f0; ACC.y += ww * f1; ACC.z += ww * f2; ACC.w += ww * f3; \
      }
      for (; i + 4 <= steps; i += 4) {
        GATHER_ONE(i * 4 + g, acc)
        GATHER_ONE(i * 4 + 4 + g, acc)
        GATHER_ONE(i * 4 + 8 + g, acc)
        GATHER_ONE(i * 4 + 12 + g, acc)
      }
      for (; i < steps; ++i) {
        GATHER_ONE(i * 4 + g, acc)
      }
#undef GATHER_ONE
    }
    acc.x += __shfl_xor(acc.x, 16); acc.y += __shfl_xor(acc.y, 16);
    acc.z += __shfl_xor(acc.z, 16); acc.w += __shfl_xor(acc.w, 16);
    acc.x += __shfl_xor(acc.x, 32); acc.y += __shfl_xor(acc.y, 32);
    acc.z += __shfl_xor(acc.z, 32); acc.w += __shfl_xor(acc.w, 32);
    float ci = (degc > 0) ? (1.0f / (float)degc) : 1.0f;
    if (g == 0) {
      *reinterpret_cast<float4*>(&sAgg[wave][l16 * 4]) =
          make_float4(acc.x * ci, acc.y * ci, acc.z * ci, acc.w * ci);
    }
    sX[wave][lane] = bf2f(A[(size_t)n * kD + lane]);
    // wave-local LDS producer/consumer: compiler inserts lgkmcnt waits.
    float o = bias;
#pragma unroll
    for (int k4 = 0; k4 < 16; ++k4) {
      float4 ag = *reinterpret_cast<const float4*>(&sAgg[wave][k4 * 4]);
      float4 xv = *reinterpret_cast<const float4*>(&sX[wave][k4 * 4]);
      float4 wl = *reinterpret_cast<const float4*>(&sWl[k4 * 4]);
      float4 wr = *reinterpret_cast<const float4*>(&sWr[k4 * 4]);
      o += ag.x * wl.x + ag.y * wl.y + ag.z * wl.z + ag.w * wl.w;
      o += xv.x * wr.x + xv.y * wr.y + xv.z * wr.z + xv.w * wr.w;
    }
    if (relu) o = fmaxf(o, 0.0f);
    if (B16) B16[(size_t)n * kD + lane] = f2bf(o);
    else     Bf[(size_t)n * kD + lane] = o;
  }
}

extern "C" void kernel_launch(void* const* d_in, const int* in_sizes, int n_in,
                              void* d_out, int out_size, void* d_ws, size_t ws_size,
                              hipStream_t stream) {
  const float* x   = (const float*)d_in[0];
  const int*   ei  = (const int*)d_in[1];
  const float* ew  = (const float*)d_in[2];
  const float* Wl0 = (const float*)d_in[3];
  const float* bl0 = (const float*)d_in[4];
  const float* Wr0 = (const float*)d_in[5];
  const float* Wl1 = (const float*)d_in[6];
  const float* bl1 = (const float*)d_in[7];
  const float* Wr1 = (const float*)d_in[8];
  const float* Wl2 = (const float*)d_in[9];
  const float* bl2 = (const float*)d_in[10];
  const float* Wr2 = (const float*)d_in[11];
  float* out = (float*)d_out;

  const int N = in_sizes[0] / kD;
  const int E = in_sizes[2];
  const int* row = ei;
  const int* col = ei + E;

  const int nb256 = (N + 255) / 256;

  // workspace: csr[E] int2 | xb,h1,h2 bf16 N*64 | deg,cnt,fillcnt,rowptr,incl,bsum,boff
  char* p = (char*)d_ws;
  int2*     csr     = (int2*)p;     p += (size_t)E * sizeof(int2);
  ushort_t* xb      = (ushort_t*)p; p += (size_t)N * kD * sizeof(ushort_t);
  ushort_t* h1      = (ushort_t*)p; p += (size_t)N * kD * sizeof(ushort_t);
  ushort_t* h2      = (ushort_t*)p; p += (size_t)N * kD * sizeof(ushort_t);
  float*    deg     = (float*)p;    p += (size_t)N * sizeof(float);
  uint_t*   cnt     = (uint_t*)p;   p += (size_t)N * sizeof(uint_t);
  uint_t*   fillcnt = (uint_t*)p;   p += (size_t)N * sizeof(uint_t);
  uint_t*   rowptr  = (uint_t*)p;   p += (size_t)(N + 1) * sizeof(uint_t);
  uint_t*   incl    = (uint_t*)p;   p += (size_t)N * sizeof(uint_t);
  uint_t*   bsum    = (uint_t*)p;   p += (size_t)nb256 * sizeof(uint_t);
  uint_t*   boff    = (uint_t*)p;

  const int eb = (E + 255) / 256;

  hipMemsetAsync(deg, 0, 3 * (size_t)N * sizeof(float), stream);
  k_edge_deg<<<eb, 256, 0, stream>>>(col, ew, deg, cnt, E);
  k_node_pre<<<nb256, 256, 0, stream>>>(deg, N);
  k_scanA<<<nb256, 256, 0, stream>>>(cnt, incl, bsum, N);
  k_scanB<<<1, 512, 0, stream>>>(bsum, boff, nb256);
  k_scanC<<<nb256, 256, 0, stream>>>(incl, cnt, boff, rowptr, N);
  k_fill<<<eb, 256, 0, stream>>>(row, col, ew, deg, rowptr, fillcnt, csr, E);
  k_cvt<<<(N * kD + 255) / 256, 256, 0, stream>>>(x, xb, N * kD);

  const int blocks = 1024;
  const int nwaves = blocks * 8;
  k_layer<<<blocks, 512, 0, stream>>>(xb, h1, nullptr, csr, rowptr, Wl0, bl0, Wr0, N, 1, nwaves);
  k_layer<<<blocks, 512, 0, stream>>>(h1, h2, nullptr, csr, rowptr, Wl1, bl1, Wr1, N, 1, nwaves);
  k_layer<<<blocks, 512, 0, stream>>>(h2, nullptr, out, csr, rowptr, Wl2, bl2, Wr2, N, 0, nwaves);
}